// Round 7
// baseline (342.582 us; speedup 1.0000x reference)
//
#include <hip/hip_runtime.h>
#include <hip/hip_bf16.h>

// Problem constants (Qwen3-Next linear attention defaults)
#define S_LEN   256
#define HID     2048
#define NVH     32
#define DKD     128
#define DVD     128
#define KEYDIM  512
#define VALDIM  4096
#define CONVDIM 5120
#define QKVZ_N  9216
#define EPS_F   1e-6f

typedef __attribute__((ext_vector_type(8))) short bf16x8;
typedef __attribute__((ext_vector_type(4))) float f32x4;

__device__ __forceinline__ unsigned short f2bf(float f) {
    union { float f; unsigned int i; } v; v.f = f;
    unsigned int x = v.i;
    return (unsigned short)((x + 0x7FFFu + ((x >> 16) & 1u)) >> 16); // RNE
}
__device__ __forceinline__ unsigned int pk2(float x, float y) {
    union { __hip_bfloat162 h; unsigned int u; } c;
    c.h = __float22bfloat162_rn(float2{x, y});
    return c.u;
}
__device__ __forceinline__ bf16x8 pack_bf8(float4 lo, float4 hi) {
    union { uint4 u; bf16x8 h; } c;
    c.u.x = pk2(lo.x, lo.y); c.u.y = pk2(lo.z, lo.w);
    c.u.z = pk2(hi.x, hi.y); c.u.w = pk2(hi.z, hi.w);
    return c.h;
}

// ---------------------------------------------------------------------------
// Barrier-free streaming MFMA GEMM: Cpart[z] = A[256,KC-chunk] @ B[N,KC-chunk]^T.
// NO LDS, NO barriers. Each wave owns 16 cols x all 256 rows x KC k-range:
//   per 32-k slice: 1 B-frag (2x float4 fp32 from HBM -> cvt bf16) +
//   16 A-frags (bf16x8 straight from global; A is 1-2MB, L2-resident, and the
//   block's 4 waves read the same A k-slice -> L1 hits) + 16 MFMA.
// MFMA frag layouts ARE 16B/lane contiguous (row=l16, k=quad*8+j), so global
// loads feed MFMA operands directly. Rationale: 7 prior LDS+barrier variants
// all plateaued at 47-65us / ~2TB/s because every barrier empties the CU's
// memory pipe (avg in-flight ~7KB/CU vs 22KB needed for 6.3TB/s); the
// harness's barrier-free fill kernel hits 6.7TB/s at 8% occupancy. Free-
// running waves + compiler-counted vmcnt = continuous issue (TLP like a copy
// kernel, but the bytes flow through MFMA).
// ---------------------------------------------------------------------------
template<int KC>
__global__ __launch_bounds__(256, 2)
void gemm_stream(const unsigned short* __restrict__ A, const float* __restrict__ B,
                 float* __restrict__ Cpart, int N, int K) {
    const int tid  = threadIdx.x;
    const int lane = tid & 63, wave = tid >> 6;
    const int l16 = lane & 15, quad = lane >> 4;
    const int n0 = blockIdx.x * 64 + wave * 16;   // wave's 16-col strip
    const int kbeg = blockIdx.y * KC;

    // lane-invariant-per-i bases: compiler folds i*16*K into SGPR adds and
    // keeps ONE voffset; ks offsets are unroll-constant immediates.
    const unsigned short* a0 = A + (size_t)l16 * K + kbeg + quad * 8;
    const float*          b0 = B + (size_t)(n0 + l16) * K + kbeg + quad * 8;

    f32x4 acc[16];
#pragma unroll
    for (int i = 0; i < 16; i++) acc[i] = (f32x4){0.f, 0.f, 0.f, 0.f};

#pragma unroll 4
    for (int ks = 0; ks < KC; ks += 32) {
        float4 x = *(const float4*)(b0 + ks);
        float4 y = *(const float4*)(b0 + ks + 4);
        bf16x8 bf = pack_bf8(x, y);
#pragma unroll
        for (int i = 0; i < 16; i++) {
            bf16x8 af = *(const bf16x8*)(a0 + (size_t)i * 16 * K + ks);
            acc[i] = __builtin_amdgcn_mfma_f32_16x16x32_bf16(af, bf, acc[i], 0, 0, 0);
        }
    }

    // C/D layout: col = l16, row = quad*4 + r (per m-frag i: +16*i)
    float* C = Cpart + (size_t)blockIdx.y * 256 * N + n0 + l16;
#pragma unroll
    for (int i = 0; i < 16; i++)
#pragma unroll
        for (int r = 0; r < 4; r++)
            C[(size_t)(i * 16 + quad * 4 + r) * N] = acc[i][r];
}

// sum P split-K partials (each n floats apart), float4-vectorized
template<int P>
__global__ void reduce_sum(const float* __restrict__ part, float* __restrict__ out, int n) {
    int i = (blockIdx.x * 256 + threadIdx.x) * 4;
    if (i >= n) return;
    float4 s = *(const float4*)(part + i);
#pragma unroll
    for (int p = 1; p < P; p++) {
        float4 v = *(const float4*)(part + (size_t)p * n + i);
        s.x += v.x; s.y += v.y; s.z += v.z; s.w += v.w;
    }
    *(float4*)(out + i) = s;
}

// ba = hidden @ w_ba^T : [256,64] + emit hs row in bf16 (A of GEMM1).
__global__ __launch_bounds__(256)
void ba_proj_cvt(const float* __restrict__ hs, const float* __restrict__ w_ba,
                 float* __restrict__ ba, unsigned short* __restrict__ abf) {
    int s = blockIdx.x;
    int n = threadIdx.x & 63, seg = threadIdx.x >> 6;
    const float* x = hs + (size_t)s * HID + seg * 512;
    const float* w = w_ba + (size_t)n * HID + seg * 512;
    float acc = 0.f;
#pragma unroll 4
    for (int k = 0; k < 512; k += 4) {
        float4 xv = *(const float4*)(x + k);
        float4 wv = *(const float4*)(w + k);
        acc += xv.x * wv.x + xv.y * wv.y + xv.z * wv.z + xv.w * wv.w;
    }
    __shared__ float parts[4][64];
    parts[seg][n] = acc;
    {   // bf16 copy of this row: thread converts 8 elems (L1-hot reread)
        int d = threadIdx.x * 8;
        const float4* p = (const float4*)(hs + (size_t)s * HID + d);
        float4 a = p[0], b = p[1];
        uint4 r;
        r.x = pk2(a.x, a.y); r.y = pk2(a.z, a.w);
        r.z = pk2(b.x, b.y); r.w = pk2(b.z, b.w);
        *(uint4*)(abf + (size_t)s * HID + d) = r;
    }
    __syncthreads();
    if (threadIdx.x < 64)
        ba[s * 64 + threadIdx.x] = parts[0][threadIdx.x] + parts[1][threadIdx.x]
                                 + parts[2][threadIdx.x] + parts[3][threadIdx.x];
}

// Fused: split-K sum of qkvz partials + causal depthwise conv(K=4) + silu for
// qkv cols (<5120), plain sum for z cols (>=5120, compact zs buffer).
// Thread = 4 cols (float4); block = 1024 cols x 8 s; conv window in regs.
template<int P>
__global__ __launch_bounds__(256)
void sum_conv(const float* __restrict__ part, const float* __restrict__ conv_w,
              float* __restrict__ conv, float* __restrict__ zs) {
    const int s0 = blockIdx.y * 8;
    const int c  = blockIdx.x * 1024 + threadIdx.x * 4;
    auto sum4 = [&](int s) {
        const float* p = part + (size_t)s * QKVZ_N + c;
        float4 v = *(const float4*)p;
#pragma unroll
        for (int q = 1; q < P; q++) {
            float4 w = *(const float4*)(p + (size_t)q * S_LEN * QKVZ_N);
            v.x += w.x; v.y += w.y; v.z += w.z; v.w += w.w;
        }
        return v;
    };
    if (c < CONVDIM) {
        float4 cw[4];
#pragma unroll
        for (int i = 0; i < 4; ++i) cw[i] = *(const float4*)(conv_w + (size_t)(c + i) * 4);
        float4 w0{0,0,0,0}, w1{0,0,0,0}, w2{0,0,0,0};
        for (int s = (s0 >= 3 ? s0 - 3 : 0); s < s0; ++s) { w0 = w1; w1 = w2; w2 = sum4(s); }
        for (int s = s0; s < s0 + 8; ++s) {
            float4 w3 = sum4(s);
            float4 o;
            o.x = w0.x * cw[0].x + w1.x * cw[0].y + w2.x * cw[0].z + w3.x * cw[0].w;
            o.y = w0.y * cw[1].x + w1.y * cw[1].y + w2.y * cw[1].z + w3.y * cw[1].w;
            o.z = w0.z * cw[2].x + w1.z * cw[2].y + w2.z * cw[2].z + w3.z * cw[2].w;
            o.w = w0.w * cw[3].x + w1.w * cw[3].y + w2.w * cw[3].z + w3.w * cw[3].w;
            o.x = o.x / (1.f + __expf(-o.x));
            o.y = o.y / (1.f + __expf(-o.y));
            o.z = o.z / (1.f + __expf(-o.z));
            o.w = o.w / (1.f + __expf(-o.w));
            *(float4*)(conv + (size_t)s * CONVDIM + c) = o;
            w0 = w1; w1 = w2; w2 = w3;
        }
    } else {
        for (int s = s0; s < s0 + 8; ++s) {
            float4 v = sum4(s);
            *(float4*)(zs + (size_t)s * VALDIM + (c - CONVDIM)) = v;
        }
    }
}

// scores[n][s][t] = (t<=s) ? (q[s]·k[t]) * DK^-0.5 * sigmoid(beta[t,n]+dt_bias[n]) : 0
// GQA: dot depends only on hk = n>>3 -> compute once, fan out over 8 v-heads.
// Triangular launch: blockIdx.x in [0,136) decodes to (s_tile >= t_tile).
__global__ __launch_bounds__(256)
void scores_k(const float* __restrict__ conv, const float* __restrict__ ba,
              const float* __restrict__ dt_bias, float* __restrict__ scores) {
    int p = blockIdx.x;
    int st = (int)((__fsqrt_rn(8.f * p + 1.f) - 1.f) * 0.5f);
    while ((st + 1) * (st + 2) / 2 <= p) st++;
    while (st * (st + 1) / 2 > p) st--;
    int tt = p - st * (st + 1) / 2;
    int hk = blockIdx.y;
    int s0 = st * 16, t0 = tt * 16;
    __shared__ float Qs[16][132], Ks[16][132];
    int tid = threadIdx.x;
    int qoff = hk * DKD;
    int koff = KEYDIM + hk * DKD;
    for (int idx = tid; idx < 16 * 128; idx += 256) {
        int i = idx >> 7, d = idx & 127;
        Qs[i][d] = conv[(size_t)(s0 + i) * CONVDIM + qoff + d];
        Ks[i][d] = conv[(size_t)(t0 + i) * CONVDIM + koff + d];
    }
    __syncthreads();
    int tx = tid & 15, ty = tid >> 4;
    int s = s0 + ty, t = t0 + tx;
    float dot = 0.f;
    for (int d = 0; d < 128; d++) dot += Qs[ty][d] * Ks[tx][d];
    float base = (t <= s) ? dot * 0.08838834764831845f : 0.f;
#pragma unroll
    for (int v = 0; v < 8; v++) {
        int n = hk * 8 + v;
        float b = ba[t * 64 + n] + dt_bias[n];
        float bg = 1.f / (1.f + __expf(-b));
        scores[((size_t)n * 256 + s) * 256 + t] = base * bg;
    }
}

// Fused attn + gated RMSNorm: attn[s][n][:] = sum_t scores[n][s][t]*v[t][n][:]
// stays in registers; 16-lane shfl_xor gives the row sum-of-squares; gate with
// silu(z); emit bf16 directly.
__global__ __launch_bounds__(256)
void attn_rms(const float* __restrict__ scores, const float* __restrict__ conv,
              const float* __restrict__ zs, const float* __restrict__ norm_w,
              unsigned short* __restrict__ normed) {
    int n = blockIdx.y, s0 = blockIdx.x * 16;
    int voff = 2 * KEYDIM + n * DVD;
    __shared__ float Ss[16][17];
    __shared__ float Vs[16][132];
    int tid = threadIdx.x, sy = tid >> 4, dx = tid & 15;
    float acc[8] = {0.f, 0.f, 0.f, 0.f, 0.f, 0.f, 0.f, 0.f};
    for (int t0 = 0; t0 <= s0; t0 += 16) {
        Ss[sy][dx] = scores[((size_t)n * 256 + s0 + sy) * 256 + t0 + dx];
        const float* vp = conv + (size_t)(t0 + sy) * CONVDIM + voff + dx * 8;
        *(float4*)&Vs[sy][dx * 8]     = *(const float4*)vp;
        *(float4*)&Vs[sy][dx * 8 + 4] = *(const float4*)(vp + 4);
        __syncthreads();
#pragma unroll
        for (int j = 0; j < 16; j++) {
            float sv = Ss[sy][j];
#pragma unroll
            for (int r = 0; r < 8; r++) acc[r] += sv * Vs[j][dx + 16 * r];
        }
        __syncthreads();
    }
    float ssq = 0.f;
#pragma unroll
    for (int r = 0; r < 8; r++) ssq += acc[r] * acc[r];
#pragma unroll
    for (int m = 1; m <= 8; m <<= 1) ssq += __shfl_xor(ssq, m, 64); // 16-lane group
    float inv = rsqrtf(ssq * (1.f / 128.f) + EPS_F);
    int s = s0 + sy;
#pragma unroll
    for (int r = 0; r < 8; r++) {
        int d = dx + 16 * r;
        float z = zs[(size_t)s * VALDIM + n * DVD + d];
        float sz = z / (1.f + __expf(-z));
        float v = acc[r] * inv * norm_w[d] * sz;
        normed[((size_t)s * NVH + n) * DVD + d] = f2bf(v);
    }
}

extern "C" void kernel_launch(void* const* d_in, const int* in_sizes, int n_in,
                              void* d_out, int out_size, void* d_ws, size_t ws_size,
                              hipStream_t stream) {
    const float* hs      = (const float*)d_in[0];
    const float* w_qkvz  = (const float*)d_in[1];
    const float* w_ba    = (const float*)d_in[2];
    const float* w_out   = (const float*)d_in[3];
    const float* conv_w  = (const float*)d_in[4];
    const float* dt_bias = (const float*)d_in[5];
    const float* norm_w  = (const float*)d_in[7];

    // Workspace overlay. Front: long-lived (abf, ba, conv, zs ~10.5 MB).
    // Region B (time-multiplexed): scratch1 (steps 2-3) overlaps
    // normed/scratch2/scores (steps 4-7).
    char* ws = (char*)d_ws;
    unsigned short* abf = (unsigned short*)ws; ws += (size_t)S_LEN * HID * 2;     // 1.05 MB
    float* ba   = (float*)ws;  ws += (size_t)S_LEN * 64 * 4;                      // 64 KB
    float* conv = (float*)ws;  ws += (size_t)S_LEN * CONVDIM * 4;                 // 5.24 MB
    float* zs   = (float*)ws;  ws += (size_t)S_LEN * VALDIM * 4;                  // 4.19 MB
    char* regB = ws;
    const bool big = ws_size >= (size_t)60 * 1024 * 1024;
    const int sk1 = big ? 4 : 2;    // gemm1 split-K
    const int sk2 = big ? 16 : 8;   // gemm2 split-K
    float* scratch1 = (float*)regB;                                   // sk1 x 9.44 MB
    unsigned short* normed = (unsigned short*)regB;                   // 2.10 MB
    float* scratch2 = (float*)(regB + 2097152);                       // sk2 x 2.10 MB
    float* scores   = (float*)(regB + 2097152 + (size_t)sk2 * 2097152); // 8.39 MB

    // 1) ba = X @ Wba^T  and hs -> bf16 A-operand
    ba_proj_cvt<<<S_LEN, 256, 0, stream>>>(hs, w_ba, ba, abf);
    // 2) qkvz partials = X @ Wqkvz^T (M=256,N=9216,K=2048): barrier-free stream
    if (big) gemm_stream<512> <<<dim3(QKVZ_N / 64, 4), 256, 0, stream>>>(abf, w_qkvz, scratch1, QKVZ_N, HID);
    else     gemm_stream<1024><<<dim3(QKVZ_N / 64, 2), 256, 0, stream>>>(abf, w_qkvz, scratch1, QKVZ_N, HID);
    // 3) fused split-K sum + causal conv + silu (qkv) / plain sum (z)
    if (big) sum_conv<4><<<dim3(9, 32), 256, 0, stream>>>(scratch1, conv_w, conv, zs);
    else     sum_conv<2><<<dim3(9, 32), 256, 0, stream>>>(scratch1, conv_w, conv, zs);
    // 4) causal scores, triangular grid (dot once per k-head, fan out 8 v-heads)
    scores_k<<<dim3(136, 4), 256, 0, stream>>>(conv, ba, dt_bias, scores);
    // 5) fused attn + gated RMSNorm -> bf16
    attn_rms<<<dim3(16, NVH), 256, 0, stream>>>(scores, conv, zs, norm_w, normed);
    // 6) out partials = normed @ Wout^T (M=256,N=2048,K=4096): barrier-free stream
    if (big) gemm_stream<256><<<dim3(HID / 64, 16), 256, 0, stream>>>(normed, w_out, scratch2, HID, VALDIM);
    else     gemm_stream<512><<<dim3(HID / 64,  8), 256, 0, stream>>>(normed, w_out, scratch2, HID, VALDIM);
    // 7) reduce split-K -> d_out (fp32)
    if (big) reduce_sum<16><<<(S_LEN * HID) / 1024, 256, 0, stream>>>(scratch2, (float*)d_out, S_LEN * HID);
    else     reduce_sum<8> <<<(S_LEN * HID) / 1024, 256, 0, stream>>>(scratch2, (float*)d_out, S_LEN * HID);
}

// Round 8
// 253.847 us; speedup vs baseline: 1.3496x; 1.3496x over previous
//
#include <hip/hip_runtime.h>
#include <hip/hip_bf16.h>

// Problem constants (Qwen3-Next linear attention defaults)
#define S_LEN   256
#define HID     2048
#define NVH     32
#define DKD     128
#define DVD     128
#define KEYDIM  512
#define VALDIM  4096
#define CONVDIM 5120
#define QKVZ_N  9216
#define EPS_F   1e-6f

typedef __attribute__((ext_vector_type(8))) short bf16x8;
typedef __attribute__((ext_vector_type(4))) float f32x4;

__device__ __forceinline__ unsigned short f2bf(float f) {
    union { float f; unsigned int i; } v; v.f = f;
    unsigned int x = v.i;
    return (unsigned short)((x + 0x7FFFu + ((x >> 16) & 1u)) >> 16); // RNE
}
__device__ __forceinline__ unsigned int pk2(float x, float y) {
    union { __hip_bfloat162 h; unsigned int u; } c;
    c.h = __float22bfloat162_rn(float2{x, y});
    return c.u;
}
__device__ __forceinline__ bf16x8 pack_bf8(float4 lo, float4 hi) {
    union { uint4 u; bf16x8 h; } c;
    c.u.x = pk2(lo.x, lo.y); c.u.y = pk2(lo.z, lo.w);
    c.u.z = pk2(hi.x, hi.y); c.u.w = pk2(hi.z, hi.w);
    return c.h;
}
// 16B global -> LDS DMA. LDS dest = wave-uniform base + lane*16 (linear).
__device__ __forceinline__ void gl_lds16(const void* g, void* l) {
    __builtin_amdgcn_global_load_lds(
        (const __attribute__((address_space(1))) unsigned int*)g,
        (__attribute__((address_space(3))) unsigned int*)l,
        16, 0, 0);
}

// ---------------------------------------------------------------------------
// Stream-N split-K GEMM (round-2 structure, best measured: 46.9us for gemm1
// across 7 tried schedules): Cpart[z] = A[256,Kc] @ B[N,Kc]^T.
// A bf16 [256][K], B fp32 [N][K] streamed from HBM exactly once (no N-tile
// duplication: wave = 64 M-rows x NT cols, M=256 covered by the 4 waves).
// Staging via global_load_lds for BOTH operands; serial stage->sync->compute
// loop at 3-4 blocks/CU (48/40KB LDS). Pipelined/dbuf variants measured equal
// or slower (rounds 3-6); barrier-free direct-global 2.3x slower (round 7).
// XOR-(row&7) swizzle on the GLOBAL source (LDS linear); A frag reads
// measured 0 conflicts; B fp32 float4 reads +4cy each (measured, accepted).
// ---------------------------------------------------------------------------
template<int NT>
__global__ __launch_bounds__(256, 3)
void gemm_sn(const unsigned short* __restrict__ A, const float* __restrict__ B,
             float* __restrict__ Cpart, int N, int K, int kc) {
    __shared__ __align__(16) unsigned short As[256][64];
    __shared__ __align__(16) float Bs[NT][64];

    const int tid  = threadIdx.x;
    const int lane = tid & 63, wave = tid >> 6;
    const int quad = lane >> 4, l16 = lane & 15;
    const int n0 = blockIdx.x * NT;
    const int kbeg = blockIdx.y * kc;
    const int niter = kc >> 6;                 // BK = 64
    constexpr int NB = NT / 16;                // N-frags per wave

    // A staging: 8 insts/wave; inst t covers rows wave*64+t*8 .. +7.
    const int a_ro = lane >> 3;
    const int a_gc = (lane & 7) ^ a_ro;        // (row&7) == lane>>3 here
    // B staging: NT/16 insts/wave; inst t covers rows wave*(NT/4)+t*4 .. +3.
    const int b_ro = lane >> 4;
    const int b_cs = lane & 15;

    f32x4 acc[4][NB];
#pragma unroll
    for (int i = 0; i < 4; i++)
#pragma unroll
        for (int j = 0; j < NB; j++) acc[i][j] = (f32x4){0.f, 0.f, 0.f, 0.f};

    auto stage = [&](int kk) {
#pragma unroll
        for (int t = 0; t < 8; ++t) {
            int rbase = wave * 64 + t * 8;
            gl_lds16(A + (size_t)(rbase + a_ro) * K + kk + a_gc * 8,
                     &As[rbase][0]);
        }
#pragma unroll
        for (int t = 0; t < NT / 16; ++t) {
            int rbase = wave * (NT / 4) + t * 4;
            int r = rbase + b_ro;
            int gc = b_cs ^ (r & 7);
            gl_lds16(B + (size_t)(n0 + r) * K + kk + gc * 4,
                     &Bs[rbase][0]);
        }
    };

    auto compute = [&]() {
#pragma unroll
        for (int ks = 0; ks < 2; ++ks) {
            bf16x8 af[4];
#pragma unroll
            for (int i = 0; i < 4; ++i) {
                int r = wave * 64 + i * 16 + l16;
                int c = (ks * 4 + quad) ^ (l16 & 7);
                af[i] = *(const bf16x8*)(&As[r][c * 8]);
            }
#pragma unroll
            for (int j = 0; j < NB; ++j) {
                int r = j * 16 + l16;
                int x = l16 & 7;
                int c0 = (ks * 8 + quad * 2) ^ x;
                int c1 = (ks * 8 + quad * 2 + 1) ^ x;
                float4 lo = *(const float4*)(&Bs[r][c0 * 4]);
                float4 hi = *(const float4*)(&Bs[r][c1 * 4]);
                bf16x8 bfr = pack_bf8(lo, hi);
#pragma unroll
                for (int i = 0; i < 4; ++i)
                    acc[i][j] = __builtin_amdgcn_mfma_f32_16x16x32_bf16(af[i], bfr, acc[i][j], 0, 0, 0);
            }
        }
    };

    stage(kbeg);
    for (int it = 0; it < niter; ++it) {
        __syncthreads();                       // drains DMA (vmcnt) + lgkm
        compute();
        if (it + 1 < niter) {
            __syncthreads();                   // all frag reads done
            stage(kbeg + (it + 1) * 64);
        }
    }

    float* C = Cpart + (size_t)blockIdx.y * 256 * N;
#pragma unroll
    for (int i = 0; i < 4; i++)
#pragma unroll
        for (int j = 0; j < NB; j++)
#pragma unroll
            for (int r = 0; r < 4; r++) {
                int row = wave * 64 + i * 16 + quad * 4 + r;
                int col = n0 + j * 16 + l16;
                C[(size_t)row * N + col] = acc[i][j][r];
            }
}

// sum P split-K partials (each n floats apart), float4-vectorized
template<int P>
__global__ void reduce_sum(const float* __restrict__ part, float* __restrict__ out, int n) {
    int i = (blockIdx.x * 256 + threadIdx.x) * 4;
    if (i >= n) return;
    float4 s = *(const float4*)(part + i);
#pragma unroll
    for (int p = 1; p < P; p++) {
        float4 v = *(const float4*)(part + (size_t)p * n + i);
        s.x += v.x; s.y += v.y; s.z += v.z; s.w += v.w;
    }
    *(float4*)(out + i) = s;
}

// ba = hidden @ w_ba^T : [256,64] + emit hs row in bf16 (A of GEMM1).
__global__ __launch_bounds__(256)
void ba_proj_cvt(const float* __restrict__ hs, const float* __restrict__ w_ba,
                 float* __restrict__ ba, unsigned short* __restrict__ abf) {
    int s = blockIdx.x;
    int n = threadIdx.x & 63, seg = threadIdx.x >> 6;
    const float* x = hs + (size_t)s * HID + seg * 512;
    const float* w = w_ba + (size_t)n * HID + seg * 512;
    float acc = 0.f;
#pragma unroll 4
    for (int k = 0; k < 512; k += 4) {
        float4 xv = *(const float4*)(x + k);
        float4 wv = *(const float4*)(w + k);
        acc += xv.x * wv.x + xv.y * wv.y + xv.z * wv.z + xv.w * wv.w;
    }
    __shared__ float parts[4][64];
    parts[seg][n] = acc;
    {   // bf16 copy of this row: thread converts 8 elems (L1-hot reread)
        int d = threadIdx.x * 8;
        const float4* p = (const float4*)(hs + (size_t)s * HID + d);
        float4 a = p[0], b = p[1];
        uint4 r;
        r.x = pk2(a.x, a.y); r.y = pk2(a.z, a.w);
        r.z = pk2(b.x, b.y); r.w = pk2(b.z, b.w);
        *(uint4*)(abf + (size_t)s * HID + d) = r;
    }
    __syncthreads();
    if (threadIdx.x < 64)
        ba[s * 64 + threadIdx.x] = parts[0][threadIdx.x] + parts[1][threadIdx.x]
                                 + parts[2][threadIdx.x] + parts[3][threadIdx.x];
}

// Fused: split-K sum of qkvz partials + causal depthwise conv(K=4) + silu for
// qkv cols (<5120), plain sum for z cols (>=5120, compact zs buffer).
// Thread = 4 cols (float4); block = 1024 cols x 8 s; conv window in regs.
template<int P>
__global__ __launch_bounds__(256)
void sum_conv(const float* __restrict__ part, const float* __restrict__ conv_w,
              float* __restrict__ conv, float* __restrict__ zs) {
    const int s0 = blockIdx.y * 8;
    const int c  = blockIdx.x * 1024 + threadIdx.x * 4;
    auto sum4 = [&](int s) {
        const float* p = part + (size_t)s * QKVZ_N + c;
        float4 v = *(const float4*)p;
#pragma unroll
        for (int q = 1; q < P; q++) {
            float4 w = *(const float4*)(p + (size_t)q * S_LEN * QKVZ_N);
            v.x += w.x; v.y += w.y; v.z += w.z; v.w += w.w;
        }
        return v;
    };
    if (c < CONVDIM) {
        float4 cw[4];
#pragma unroll
        for (int i = 0; i < 4; ++i) cw[i] = *(const float4*)(conv_w + (size_t)(c + i) * 4);
        float4 w0{0,0,0,0}, w1{0,0,0,0}, w2{0,0,0,0};
        for (int s = (s0 >= 3 ? s0 - 3 : 0); s < s0; ++s) { w0 = w1; w1 = w2; w2 = sum4(s); }
        for (int s = s0; s < s0 + 8; ++s) {
            float4 w3 = sum4(s);
            float4 o;
            o.x = w0.x * cw[0].x + w1.x * cw[0].y + w2.x * cw[0].z + w3.x * cw[0].w;
            o.y = w0.y * cw[1].x + w1.y * cw[1].y + w2.y * cw[1].z + w3.y * cw[1].w;
            o.z = w0.z * cw[2].x + w1.z * cw[2].y + w2.z * cw[2].z + w3.z * cw[2].w;
            o.w = w0.w * cw[3].x + w1.w * cw[3].y + w2.w * cw[3].z + w3.w * cw[3].w;
            o.x = o.x / (1.f + __expf(-o.x));
            o.y = o.y / (1.f + __expf(-o.y));
            o.z = o.z / (1.f + __expf(-o.z));
            o.w = o.w / (1.f + __expf(-o.w));
            *(float4*)(conv + (size_t)s * CONVDIM + c) = o;
            w0 = w1; w1 = w2; w2 = w3;
        }
    } else {
        for (int s = s0; s < s0 + 8; ++s) {
            float4 v = sum4(s);
            *(float4*)(zs + (size_t)s * VALDIM + (c - CONVDIM)) = v;
        }
    }
}

// scores[n][s][t] = (t<=s) ? (q[s]·k[t]) * DK^-0.5 * sigmoid(beta[t,n]+dt_bias[n]) : 0
// GQA: dot depends only on hk = n>>3 -> compute once, fan out over 8 v-heads.
// Triangular launch: blockIdx.x in [0,136) decodes to (s_tile >= t_tile).
__global__ __launch_bounds__(256)
void scores_k(const float* __restrict__ conv, const float* __restrict__ ba,
              const float* __restrict__ dt_bias, float* __restrict__ scores) {
    int p = blockIdx.x;
    int st = (int)((__fsqrt_rn(8.f * p + 1.f) - 1.f) * 0.5f);
    while ((st + 1) * (st + 2) / 2 <= p) st++;
    while (st * (st + 1) / 2 > p) st--;
    int tt = p - st * (st + 1) / 2;
    int hk = blockIdx.y;
    int s0 = st * 16, t0 = tt * 16;
    __shared__ float Qs[16][132], Ks[16][132];
    int tid = threadIdx.x;
    int qoff = hk * DKD;
    int koff = KEYDIM + hk * DKD;
    for (int idx = tid; idx < 16 * 128; idx += 256) {
        int i = idx >> 7, d = idx & 127;
        Qs[i][d] = conv[(size_t)(s0 + i) * CONVDIM + qoff + d];
        Ks[i][d] = conv[(size_t)(t0 + i) * CONVDIM + koff + d];
    }
    __syncthreads();
    int tx = tid & 15, ty = tid >> 4;
    int s = s0 + ty, t = t0 + tx;
    float dot = 0.f;
    for (int d = 0; d < 128; d++) dot += Qs[ty][d] * Ks[tx][d];
    float base = (t <= s) ? dot * 0.08838834764831845f : 0.f;
#pragma unroll
    for (int v = 0; v < 8; v++) {
        int n = hk * 8 + v;
        float b = ba[t * 64 + n] + dt_bias[n];
        float bg = 1.f / (1.f + __expf(-b));
        scores[((size_t)n * 256 + s) * 256 + t] = base * bg;
    }
}

// Fused attn + gated RMSNorm: attn[s][n][:] = sum_t scores[n][s][t]*v[t][n][:]
// stays in registers; 16-lane shfl_xor gives the row sum-of-squares; gate with
// silu(z); emit bf16 directly.
__global__ __launch_bounds__(256)
void attn_rms(const float* __restrict__ scores, const float* __restrict__ conv,
              const float* __restrict__ zs, const float* __restrict__ norm_w,
              unsigned short* __restrict__ normed) {
    int n = blockIdx.y, s0 = blockIdx.x * 16;
    int voff = 2 * KEYDIM + n * DVD;
    __shared__ float Ss[16][17];
    __shared__ float Vs[16][132];
    int tid = threadIdx.x, sy = tid >> 4, dx = tid & 15;
    float acc[8] = {0.f, 0.f, 0.f, 0.f, 0.f, 0.f, 0.f, 0.f};
    for (int t0 = 0; t0 <= s0; t0 += 16) {
        Ss[sy][dx] = scores[((size_t)n * 256 + s0 + sy) * 256 + t0 + dx];
        const float* vp = conv + (size_t)(t0 + sy) * CONVDIM + voff + dx * 8;
        *(float4*)&Vs[sy][dx * 8]     = *(const float4*)vp;
        *(float4*)&Vs[sy][dx * 8 + 4] = *(const float4*)(vp + 4);
        __syncthreads();
#pragma unroll
        for (int j = 0; j < 16; j++) {
            float sv = Ss[sy][j];
#pragma unroll
            for (int r = 0; r < 8; r++) acc[r] += sv * Vs[j][dx + 16 * r];
        }
        __syncthreads();
    }
    float ssq = 0.f;
#pragma unroll
    for (int r = 0; r < 8; r++) ssq += acc[r] * acc[r];
#pragma unroll
    for (int m = 1; m <= 8; m <<= 1) ssq += __shfl_xor(ssq, m, 64); // 16-lane group
    float inv = rsqrtf(ssq * (1.f / 128.f) + EPS_F);
    int s = s0 + sy;
#pragma unroll
    for (int r = 0; r < 8; r++) {
        int d = dx + 16 * r;
        float z = zs[(size_t)s * VALDIM + n * DVD + d];
        float sz = z / (1.f + __expf(-z));
        float v = acc[r] * inv * norm_w[d] * sz;
        normed[((size_t)s * NVH + n) * DVD + d] = f2bf(v);
    }
}

extern "C" void kernel_launch(void* const* d_in, const int* in_sizes, int n_in,
                              void* d_out, int out_size, void* d_ws, size_t ws_size,
                              hipStream_t stream) {
    const float* hs      = (const float*)d_in[0];
    const float* w_qkvz  = (const float*)d_in[1];
    const float* w_ba    = (const float*)d_in[2];
    const float* w_out   = (const float*)d_in[3];
    const float* conv_w  = (const float*)d_in[4];
    const float* dt_bias = (const float*)d_in[5];
    const float* norm_w  = (const float*)d_in[7];

    // Workspace overlay. Front: long-lived (abf, ba, conv, zs ~10.5 MB).
    // Region B: scratch1 (gemm1 partials, steps 2-3) shares space with
    // normed/scratch2/scores (steps 4-7).
    char* ws = (char*)d_ws;
    unsigned short* abf = (unsigned short*)ws; ws += (size_t)S_LEN * HID * 2;     // 1.05 MB
    float* ba   = (float*)ws;  ws += (size_t)S_LEN * 64 * 4;                      // 64 KB
    float* conv = (float*)ws;  ws += (size_t)S_LEN * CONVDIM * 4;                 // 5.24 MB
    float* zs   = (float*)ws;  ws += (size_t)S_LEN * VALDIM * 4;                  // 4.19 MB
    char* regB = ws;
    const bool big = ws_size >= (size_t)56 * 1024 * 1024;
    const int sk1 = big ? 4 : 2;    // gemm1 split-K
    const int sk2 = big ? 16 : 8;   // gemm2 split-K
    float* scratch1 = (float*)regB;                                   // sk1 x 9.44 MB
    unsigned short* normed = (unsigned short*)regB;                   // 2.10 MB
    float* scratch2 = (float*)(regB + 2097152);                       // sk2 x 2.10 MB
    float* scores   = (float*)(regB + 2097152 + (size_t)sk2 * 2097152); // 8.39 MB

    // 1) ba = X @ Wba^T  and hs -> bf16 A-operand
    ba_proj_cvt<<<S_LEN, 256, 0, stream>>>(hs, w_ba, ba, abf);
    // 2) qkvz partials = X @ Wqkvz^T (M=256,N=9216,K=2048); B streamed once
    if (big) gemm_sn<64><<<dim3(QKVZ_N / 64, 4), 256, 0, stream>>>(abf, w_qkvz, scratch1, QKVZ_N, HID, HID / 4);
    else     gemm_sn<64><<<dim3(QKVZ_N / 64, 2), 256, 0, stream>>>(abf, w_qkvz, scratch1, QKVZ_N, HID, HID / 2);
    // 3) fused split-K sum + causal conv + silu (qkv) / plain sum (z)
    if (big) sum_conv<4><<<dim3(9, 32), 256, 0, stream>>>(scratch1, conv_w, conv, zs);
    else     sum_conv<2><<<dim3(9, 32), 256, 0, stream>>>(scratch1, conv_w, conv, zs);
    // 4) causal scores, triangular grid (dot once per k-head, fan out 8 v-heads)
    scores_k<<<dim3(136, 4), 256, 0, stream>>>(conv, ba, dt_bias, scores);
    // 5) fused attn + gated RMSNorm -> bf16
    attn_rms<<<dim3(16, NVH), 256, 0, stream>>>(scores, conv, zs, norm_w, normed);
    // 6) out partials = normed @ Wout^T (M=256,N=2048,K=4096); B streamed once,
    //    NT=32 -> 40KB LDS, 4 blocks/CU, 1024 (big) / 512 blocks
    if (big) gemm_sn<32><<<dim3(HID / 32, 16), 256, 0, stream>>>(normed, w_out, scratch2, HID, VALDIM, VALDIM / 16);
    else     gemm_sn<32><<<dim3(HID / 32,  8), 256, 0, stream>>>(normed, w_out, scratch2, HID, VALDIM, VALDIM / 8);
    // 7) reduce split-K -> d_out (fp32)
    if (big) reduce_sum<16><<<(S_LEN * HID) / 1024, 256, 0, stream>>>(scratch2, (float*)d_out, S_LEN * HID);
    else     reduce_sum<8> <<<(S_LEN * HID) / 1024, 256, 0, stream>>>(scratch2, (float*)d_out, S_LEN * HID);
}